// Round 1
// baseline (1207.216 us; speedup 1.0000x reference)
//
#include <hip/hip_runtime.h>
#include <math.h>

#define B_ 32
#define HID_ 1024
#define NH_ 16
#define NKV_ 8
#define HD_ 128
#define LC_ 4096
#define RSCALE 0.08838834764831845f  // 1/sqrt(128)

// ---------------------------------------------------------------------------
// K1: qkv_raw[b][0..4095] = x[b] @ [Wq | Wk | Wv]
// grid 256 blocks x 256 thr; 16 cols/block, 16 r-parts, X tiled in LDS.
// ---------------------------------------------------------------------------
__global__ __launch_bounds__(256) void qkv_kernel(
    const float* __restrict__ x, const float* __restrict__ Wq,
    const float* __restrict__ Wk, const float* __restrict__ Wv,
    float* __restrict__ qkv) {
  __shared__ float xs[32 * 256];       // [b][256] r-tile
  __shared__ float red[16 * 16 * 32];  // [part][col][b]
  const int tid = threadIdx.x;
  const int col = tid & 15, part = tid >> 4;
  const int C0 = blockIdx.x * 16;
  const int cg = C0 + col;

  const float* W;
  int stride, cc;
  if (C0 < 2048)      { W = Wq; stride = 2048; cc = cg; }
  else if (C0 < 3072) { W = Wk; stride = 1024; cc = cg - 2048; }
  else                { W = Wv; stride = 1024; cc = cg - 3072; }

  float acc[32];
#pragma unroll
  for (int b = 0; b < 32; ++b) acc[b] = 0.f;

  for (int tile = 0; tile < 4; ++tile) {
    __syncthreads();
    const float4* x4 = (const float4*)x;
    float4* xs4 = (float4*)xs;
#pragma unroll
    for (int k = 0; k < 32; ++k) {
      int f = k * 256 + tid;           // 0..8191 float4 slots
      int b = f >> 6, rl = f & 63;     // 64 float4 per b per tile
      xs4[b * 64 + rl] = x4[b * 256 + tile * 64 + rl];
    }
    __syncthreads();
    float w[16];
#pragma unroll
    for (int i = 0; i < 16; ++i) {
      int r = tile * 256 + part * 16 + i;
      w[i] = W[(size_t)r * stride + cc];
    }
#pragma unroll
    for (int b = 0; b < 32; ++b) {
      const float4* xr = (const float4*)&xs[b * 256 + part * 16];
      float s = acc[b];
#pragma unroll
      for (int i4 = 0; i4 < 4; ++i4) {
        float4 xv = xr[i4];
        s += xv.x * w[i4 * 4 + 0] + xv.y * w[i4 * 4 + 1] +
             xv.z * w[i4 * 4 + 2] + xv.w * w[i4 * 4 + 3];
      }
      acc[b] = s;
    }
  }
  __syncthreads();
#pragma unroll
  for (int b = 0; b < 32; ++b) red[(part * 16 + col) * 32 + b] = acc[b];
  __syncthreads();
  for (int o = tid; o < 512; o += 256) {
    int c = o >> 5, b = o & 31;
    float s = 0.f;
#pragma unroll
    for (int p = 0; p < 16; ++p) s += red[(p * 16 + c) * 32 + b];
    qkv[b * 4096 + C0 + c] = s;
  }
}

// ---------------------------------------------------------------------------
// K2: per (b,g): norm+rope q0,q1,k_new; flash-decode over 4096 cache rows + 1
// grid 256 blocks (b*8+g) x 512 thr (8 waves x 512 rows each)
// ---------------------------------------------------------------------------
__global__ __launch_bounds__(512) void attn_kernel(
    const float* __restrict__ qkv, const float* __restrict__ qw,
    const float* __restrict__ kw, const float* __restrict__ kc,
    const float* __restrict__ vc, const int* __restrict__ pos,
    float* __restrict__ y) {
  __shared__ float qh[2][128];
  __shared__ float k_new[128], v_new[128];
  __shared__ float norm_tmp[4][128];
  __shared__ float ssbuf[8];
  __shared__ float comb_m[9][2], comb_l[9][2];
  __shared__ float comb_a[9][2][128];

  const int tid = threadIdx.x;
  const int b = blockIdx.x >> 3, g = blockIdx.x & 7;
  const int lane = tid & 63, wv = tid >> 6;

  // ---- Phase A: build q0,q1 (norm+rope, pre-scaled), k_new (norm+rope), v_new
  {
    int grp = tid >> 7;  // 0:q0 1:q1 2:k 3:v
    int c = tid & 127;
    int colbase;
    if (grp == 0)      colbase = (g * 2 + 0) * 128;
    else if (grp == 1) colbase = (g * 2 + 1) * 128;
    else if (grp == 2) colbase = 2048 + g * 128;
    else               colbase = 3072 + g * 128;
    float raw = qkv[b * 4096 + colbase + c];
    float sq = raw * raw;
#pragma unroll
    for (int off = 32; off; off >>= 1) sq += __shfl_xor(sq, off);
    if (lane == 0) ssbuf[wv] = sq;
    __syncthreads();
    float ss = ssbuf[grp << 1] + ssbuf[(grp << 1) | 1];
    float rinv = rsqrtf(ss * (1.0f / 128.0f) + 1e-6f);
    float nwv = (grp <= 1) ? qw[c] : kw[c];
    float val = (grp < 3) ? (nwv * raw) * rinv : raw;
    norm_tmp[grp][c] = val;
    __syncthreads();
    float outv;
    if (grp < 3) {
      int i = c & 63;
      double th = pow(1000000.0, (double)(-2 * i) / 128.0);
      float thf = (float)th;
      float fr = (float)pos[b] * thf;     // fp32 mult like reference
      float cf = (float)cos((double)fr);
      float sf = (float)sin((double)fr);
      float x1 = norm_tmp[grp][i], x2 = norm_tmp[grp][i + 64];
      outv = (c < 64) ? (x1 * cf - x2 * sf) : (x2 * cf + x1 * sf);
      if (grp <= 1) outv *= RSCALE;
    } else {
      outv = val;
    }
    if (grp == 0)      qh[0][c] = outv;
    else if (grp == 1) qh[1][c] = outv;
    else if (grp == 2) k_new[c] = outv;
    else               v_new[c] = outv;
  }
  __syncthreads();

  // ---- Phase B: stream 512 rows per wave, 4 rows/iter
  const int j = lane & 15, g16 = lane >> 4;
  float q0f[8], q1f[8];
#pragma unroll
  for (int e = 0; e < 8; ++e) {
    q0f[e] = qh[0][j * 8 + e];
    q1f[e] = qh[1][j * 8 + e];
  }
  const size_t bg = ((size_t)b * 8 + g) * (size_t)LC_ * HD_;
  const float* kb = kc + bg;
  const float* vb = vc + bg;
  const int rbase = wv * 512;

  float m0 = -INFINITY, m1 = -INFINITY, l0 = 0.f, l1 = 0.f;
  float a0[8], a1[8];
#pragma unroll
  for (int e = 0; e < 8; ++e) { a0[e] = 0.f; a1[e] = 0.f; }

  float4 kc0, kc1, vc0, vc1;
  {
    size_t off = (size_t)(rbase + g16) * 128 + j * 8;
    kc0 = ((const float4*)(kb + off))[0];
    kc1 = ((const float4*)(kb + off))[1];
    vc0 = ((const float4*)(vb + off))[0];
    vc1 = ((const float4*)(vb + off))[1];
  }
  for (int it = 0; it < 128; ++it) {
    float4 K0 = kc0, K1 = kc1, V0 = vc0, V1 = vc1;
    {
      int itn = (it + 1) & 127;  // wrap: harmless re-read
      size_t off = (size_t)(rbase + itn * 4 + g16) * 128 + j * 8;
      kc0 = ((const float4*)(kb + off))[0];
      kc1 = ((const float4*)(kb + off))[1];
      vc0 = ((const float4*)(vb + off))[0];
      vc1 = ((const float4*)(vb + off))[1];
    }
    float p0 = K0.x * q0f[0] + K0.y * q0f[1] + K0.z * q0f[2] + K0.w * q0f[3] +
               K1.x * q0f[4] + K1.y * q0f[5] + K1.z * q0f[6] + K1.w * q0f[7];
    float p1 = K0.x * q1f[0] + K0.y * q1f[1] + K0.z * q1f[2] + K0.w * q1f[3] +
               K1.x * q1f[4] + K1.y * q1f[5] + K1.z * q1f[6] + K1.w * q1f[7];
#pragma unroll
    for (int off = 8; off; off >>= 1) {
      p0 += __shfl_xor(p0, off);
      p1 += __shfl_xor(p1, off);
    }
    // cross-group (4-row) max
    float t0 = p0, t1 = p1;
    t0 = fmaxf(t0, __shfl_xor(t0, 16)); t0 = fmaxf(t0, __shfl_xor(t0, 32));
    t1 = fmaxf(t1, __shfl_xor(t1, 16)); t1 = fmaxf(t1, __shfl_xor(t1, 32));
    float mn0 = fmaxf(m0, t0), mn1 = fmaxf(m1, t1);
    float sc0 = __expf(m0 - mn0), sc1 = __expf(m1 - mn1);
    float e0 = __expf(p0 - mn0), e1 = __expf(p1 - mn1);  // own row's weight
    float se0 = e0, se1 = e1;
    se0 += __shfl_xor(se0, 16); se0 += __shfl_xor(se0, 32);
    se1 += __shfl_xor(se1, 16); se1 += __shfl_xor(se1, 32);
    l0 = l0 * sc0 + se0; l1 = l1 * sc1 + se1;
    m0 = mn0; m1 = mn1;
    float vvr[8] = {V0.x, V0.y, V0.z, V0.w, V1.x, V1.y, V1.z, V1.w};
#pragma unroll
    for (int e = 0; e < 8; ++e) {
      a0[e] = a0[e] * sc0 + e0 * vvr[e];
      a1[e] = a1[e] * sc1 + e1 * vvr[e];
    }
  }
  // reduce acc across the 4 row-groups (d = j*8+e is the same in each group)
#pragma unroll
  for (int e = 0; e < 8; ++e) {
    a0[e] += __shfl_xor(a0[e], 16); a0[e] += __shfl_xor(a0[e], 32);
    a1[e] += __shfl_xor(a1[e], 16); a1[e] += __shfl_xor(a1[e], 32);
  }
  if (g16 == 0) {
#pragma unroll
    for (int e = 0; e < 8; ++e) {
      comb_a[wv][0][j * 8 + e] = a0[e];
      comb_a[wv][1][j * 8 + e] = a1[e];
    }
    if (j == 0) {
      comb_m[wv][0] = m0; comb_m[wv][1] = m1;
      comb_l[wv][0] = l0; comb_l[wv][1] = l1;
    }
  }
  // new-token pseudo-partial (wave 0): m=s_new, l=1, acc=v_new
  if (wv == 0) {
    float p0 = qh[0][2 * lane] * k_new[2 * lane] +
               qh[0][2 * lane + 1] * k_new[2 * lane + 1];
    float p1 = qh[1][2 * lane] * k_new[2 * lane] +
               qh[1][2 * lane + 1] * k_new[2 * lane + 1];
#pragma unroll
    for (int off = 32; off; off >>= 1) {
      p0 += __shfl_xor(p0, off);
      p1 += __shfl_xor(p1, off);
    }
    comb_a[8][0][2 * lane] = v_new[2 * lane];
    comb_a[8][0][2 * lane + 1] = v_new[2 * lane + 1];
    comb_a[8][1][2 * lane] = v_new[2 * lane];
    comb_a[8][1][2 * lane + 1] = v_new[2 * lane + 1];
    if (lane == 0) {
      comb_m[8][0] = p0; comb_m[8][1] = p1;
      comb_l[8][0] = 1.f; comb_l[8][1] = 1.f;
    }
  }
  __syncthreads();

  // ---- Phase C: combine 9 partials, write y[b][g*2+h][d]
  if (tid < 256) {
    int h = tid >> 7, d = tid & 127;
    float M = -INFINITY;
#pragma unroll
    for (int w2 = 0; w2 < 9; ++w2) M = fmaxf(M, comb_m[w2][h]);
    float L = 0.f, ac = 0.f;
#pragma unroll
    for (int w2 = 0; w2 < 9; ++w2) {
      float ew = __expf(comb_m[w2][h] - M);
      L += comb_l[w2][h] * ew;
      ac += comb_a[w2][h][d] * ew;
    }
    y[(size_t)b * 2048 + (g * 2 + h) * 128 + d] = ac / L;
  }
}

// ---------------------------------------------------------------------------
// K3: out[b][0..1023] = y[b][0..2047] @ Wo
// grid 128 blocks x 256 thr; 8 cols/block, 32 r-parts, Y tiled in LDS.
// ---------------------------------------------------------------------------
__global__ __launch_bounds__(256) void out_kernel(
    const float* __restrict__ y, const float* __restrict__ Wo,
    float* __restrict__ out) {
  __shared__ float ys[32 * 256];
  __shared__ float red[32 * 8 * 32];  // [part][col][b]
  const int tid = threadIdx.x;
  const int col = tid & 7, part = tid >> 3;
  const int C0 = blockIdx.x * 8;

  float acc[32];
#pragma unroll
  for (int b = 0; b < 32; ++b) acc[b] = 0.f;

  for (int tile = 0; tile < 8; ++tile) {
    __syncthreads();
    const float4* y4 = (const float4*)y;
    float4* ys4 = (float4*)ys;
#pragma unroll
    for (int k = 0; k < 32; ++k) {
      int f = k * 256 + tid;
      int b2 = f >> 6, rl = f & 63;
      ys4[b2 * 64 + rl] = y4[b2 * 512 + tile * 64 + rl];
    }
    __syncthreads();
    float w[8];
#pragma unroll
    for (int i = 0; i < 8; ++i) {
      int r = tile * 256 + part * 8 + i;
      w[i] = Wo[(size_t)r * 1024 + C0 + col];
    }
#pragma unroll
    for (int b2 = 0; b2 < 32; ++b2) {
      const float4* yr = (const float4*)&ys[b2 * 256 + part * 8];
      float4 v0 = yr[0], v1 = yr[1];
      acc[b2] += v0.x * w[0] + v0.y * w[1] + v0.z * w[2] + v0.w * w[3] +
                 v1.x * w[4] + v1.y * w[5] + v1.z * w[6] + v1.w * w[7];
    }
  }
  __syncthreads();
#pragma unroll
  for (int b2 = 0; b2 < 32; ++b2) red[(part * 8 + col) * 32 + b2] = acc[b2];
  __syncthreads();
  {
    int o = tid;  // 256 outputs: 8 cols x 32 b
    int c = o >> 5, b2 = o & 31;
    float s = 0.f;
#pragma unroll
    for (int p = 0; p < 32; ++p) s += red[(p * 8 + c) * 32 + b2];
    out[(size_t)b2 * 1024 + C0 + c] = s;
  }
}

extern "C" void kernel_launch(void* const* d_in, const int* in_sizes, int n_in,
                              void* d_out, int out_size, void* d_ws,
                              size_t ws_size, hipStream_t stream) {
  const float* x  = (const float*)d_in[0];
  const float* Wq = (const float*)d_in[1];
  const float* Wk = (const float*)d_in[2];
  const float* Wv = (const float*)d_in[3];
  const float* Wo = (const float*)d_in[4];
  const float* qw = (const float*)d_in[5];
  const float* kw = (const float*)d_in[6];
  const float* kc = (const float*)d_in[7];
  const float* vc = (const float*)d_in[8];
  const int* sp   = (const int*)d_in[9];
  float* out = (float*)d_out;
  float* ws  = (float*)d_ws;

  float* qkv = ws;                 // 32*4096 floats
  float* yy  = ws + 32 * 4096;     // 32*2048 floats

  qkv_kernel<<<256, 256, 0, stream>>>(x, Wq, Wk, Wv, qkv);
  attn_kernel<<<256, 512, 0, stream>>>(qkv, qw, kw, kc, vc, sp, yy);
  out_kernel<<<128, 256, 0, stream>>>(yy, Wo, out);
}